// Round 4
// baseline (243.963 us; speedup 1.0000x reference)
//
#include <hip/hip_runtime.h>
#include <math.h>

typedef unsigned short ushort_t;
typedef __attribute__((ext_vector_type(8))) short bf16x8;   // MFMA A/B frag (4 VGPR)
typedef __attribute__((ext_vector_type(4))) float f32x4;    // MFMA C/D frag

// r3: the 800k device-scope atomicAdds are gone. r1 (8x MLP) and r2 (line
// padding) each moved the 50us deg pass only ~7% -> aggregate device-RMW
// throughput (~16/ns at the coherence fabric) is the ceiling, not latency or
// line conflicts. New CSR build: per-block LDS histograms (CU-local atomics),
// cross-block prefix, direct scatter. Zero global RMWs.
#define NBLK  128         // phase-1 histogram blocks (each owns E/NBLK edges)
#define MAXNH 25024       // LDS uints for packed 2x16b counters (n <= 50048)

// ---------------------------------------------------------------------------
// DPP-based add: x += x[lane ^ pattern], pure VALU.
// ---------------------------------------------------------------------------
template<int CTRL>
__device__ __forceinline__ float dpp_addf(float x)
{
    int y = __builtin_amdgcn_update_dpp(0, __float_as_int(x), CTRL, 0xf, 0xf, true);
    return x + __int_as_float(y);
}

template<int LPE>
__device__ __forceinline__ float group_reduce(float p)
{
    p = dpp_addf<0xB1>(p);                           // xor 1
    p = dpp_addf<0x4E>(p);                           // xor 2
    if constexpr (LPE >= 8)  p = dpp_addf<0x141>(p); // xor 7
    if constexpr (LPE >= 16) p = dpp_addf<0x140>(p); // xor 15
    return p;
}

__device__ __forceinline__ ushort_t f2bf(float f)
{
    unsigned u = __float_as_uint(f);
    return (ushort_t)((u + 0x7fffu + ((u >> 16) & 1u)) >> 16);   // RNE
}

// ---------------------------------------------------------------------------
// setup: convert all four weight matrices to bf16. (cnt zeroing no longer
// needed: cnt is fully written by col_scan, histG by count_hist.)
// ---------------------------------------------------------------------------
__global__ __launch_bounds__(256)
void setup_kernel(const float* __restrict__ Wl1, const float* __restrict__ Wr1,
                  const float* __restrict__ Wl2, const float* __restrict__ Wr2,
                  ushort_t* __restrict__ wab1, ushort_t* __restrict__ wab2)
{
    const int T = gridDim.x * 256;
    const int i0 = blockIdx.x * 256 + threadIdx.x;
    for (int k = i0; k < 2 * 64 * 128; k += T)
        wab1[k] = f2bf(k < 64 * 128 ? Wl1[k] : Wr1[k - 64 * 128]);
    for (int k = i0; k < 2 * 32 * 64; k += T)
        wab2[k] = f2bf(k < 32 * 64 ? Wl2[k] : Wr2[k - 32 * 64]);
}

// ---------------------------------------------------------------------------
// Phase 1: per-block LDS histogram over ALL nodes (packed 2 x 16-bit counts
// per 32-bit word; per-block per-node count <= EPB=6250 < 65536, and a field
// can never carry into its neighbor). LDS atomics are CU-local -> no fabric
// RMWs. Also emits each edge's local rank within (block, node).
// ---------------------------------------------------------------------------
__global__ __launch_bounds__(256, 1)
void count_hist(const int* __restrict__ ei, ushort_t* __restrict__ lrank,
                ushort_t* __restrict__ histG, int E, int n, int EPB)
{
    __shared__ unsigned h[MAXNH];                  // 100 KB
    const int tid = threadIdx.x;
    const int b   = blockIdx.x;
    const int nh  = (n + 1) >> 1;
    for (int i = tid; i < nh; i += 256) h[i] = 0u;
    __syncthreads();

    const int e0 = b * EPB;
    const int e1 = min(e0 + EPB, E);
    for (int e = e0 + tid; e < e1; e += 256) {
        int d = ei[E + e];
        unsigned sh  = (unsigned)(d & 1) * 16u;
        unsigned old = atomicAdd(&h[d >> 1], 1u << sh);     // LDS atomic
        lrank[e] = (ushort_t)((old >> sh) & 0xffffu);
    }
    __syncthreads();

    ushort_t* row = histG + (size_t)b * n;         // coalesced row dump
    for (int i = tid; i < n; i += 256) {
        unsigned v = h[i >> 1];
        row[i] = (ushort_t)((v >> ((i & 1) * 16)) & 0xffffu);
    }
}

// ---------------------------------------------------------------------------
// Phase 2: per-node exclusive prefix across the NBLK block rows (in place:
// histG becomes boff), plus per-node totals -> dense cnt. Loads batched 16
// deep so the L2 latency pipelines instead of serializing 128 round trips.
// ---------------------------------------------------------------------------
__global__ __launch_bounds__(256)
void col_scan(ushort_t* __restrict__ histG, int* __restrict__ cnt, int n)
{
    int idx = blockIdx.x * 256 + threadIdx.x;
    if (idx >= n) return;
    unsigned acc = 0;
    #pragma unroll 1
    for (int b0 = 0; b0 < NBLK; b0 += 16) {
        ushort_t c[16];
        #pragma unroll
        for (int j = 0; j < 16; ++j)
            c[j] = histG[(size_t)(b0 + j) * n + idx];
        #pragma unroll
        for (int j = 0; j < 16; ++j) {
            unsigned cc = c[j];
            histG[(size_t)(b0 + j) * n + idx] = (ushort_t)acc;
            acc += cc;
        }
    }
    cnt[idx] = (int)acc;
}

// ---------------------------------------------------------------------------
// scan pair (dense cnt again) — r13-proven.
// ---------------------------------------------------------------------------
__global__ __launch_bounds__(256)
void scan_p1(const int* __restrict__ cnt, int* __restrict__ bsums, int n)
{
    __shared__ int s[256];
    const int tid = threadIdx.x;
    int gi = blockIdx.x * 256 + tid;
    s[tid] = (gi < n) ? cnt[gi] : 0;
    __syncthreads();
    #pragma unroll
    for (int off = 128; off >= 1; off >>= 1) {
        if (tid < off) s[tid] += s[tid + off];
        __syncthreads();
    }
    if (tid == 0) bsums[blockIdx.x] = s[0];
}

__global__ __launch_bounds__(256)
void scan_p3(const int* __restrict__ cnt, const int* __restrict__ bsums,
             int* __restrict__ row_off, int n, int nb)
{
    __shared__ int sb[256];
    __shared__ int s[256];
    const int tid = threadIdx.x;

    int bv = (tid < nb) ? bsums[tid] : 0;
    sb[tid] = bv;
    __syncthreads();
    #pragma unroll
    for (int off = 1; off < 256; off <<= 1) {       // inclusive scan of bsums
        int t = (tid >= off) ? sb[tid - off] : 0;
        __syncthreads();
        sb[tid] += t;
        __syncthreads();
    }
    int excl_t = sb[tid] - bv;                      // exclusive
    __syncthreads();
    sb[tid] = excl_t;
    __syncthreads();
    const int base = sb[blockIdx.x];

    int gi = blockIdx.x * 256 + tid;
    int c = (gi < n) ? cnt[gi] : 0;
    s[tid] = c;
    __syncthreads();
    #pragma unroll
    for (int off = 1; off < 256; off <<= 1) {       // inclusive scan of tile
        int t = (tid >= off) ? s[tid - off] : 0;
        __syncthreads();
        s[tid] += t;
        __syncthreads();
    }
    if (gi < n) {
        int excl = base + s[tid] - c;
        row_off[gi] = excl;
        if (gi == n - 1) row_off[n] = excl + c;     // == E
    }
}

// ---------------------------------------------------------------------------
// Fused [scatter | gemm1] dispatch. Scatter path: slot position fully
// precomputed = row_off[d] + boff[e/EPB][d] + lrank[e] — no atomics at all.
// gemm1 (independent of CSR) overlaps under the scatter's random writes.
// GEMM layouts HW-verified (m89/m91); XOR-granule swizzle kills conflicts.
// ---------------------------------------------------------------------------
template<int N, int K>
__global__ __launch_bounds__(256, 2)
void scat_plus_gemm(const int* __restrict__ ei, const float* __restrict__ ew,
                    const int* __restrict__ row_off,
                    const ushort_t* __restrict__ lrank,
                    const ushort_t* __restrict__ boff,
                    int2* __restrict__ slot,
                    int E, int n, int EPB, int scatBlocks,
                    const float* __restrict__ X, const ushort_t* __restrict__ Wab,
                    const float* __restrict__ ba, const float* __restrict__ bb,
                    ushort_t* __restrict__ OutA, ushort_t* __restrict__ OutB, int M)
{
    constexpr int KC = K / 32;
    constexpr int NT = N / 16;
    __shared__ ushort_t sW[N * K];
    __shared__ ushort_t sX[64 * K];
    const int tid = threadIdx.x;

    if (blockIdx.x < scatBlocks) {              // ---- scatter path ----
        const int base = blockIdx.x * (256 * 8);
        #pragma unroll
        for (int k = 0; k < 8; ++k) {
            int e = base + k * 256 + tid;
            if (e < E) {
                int d  = ei[E + e];
                int hb = e / EPB;               // which histogram block
                int pos = row_off[d] + (int)boff[(size_t)hb * n + d]
                                     + (int)lrank[e];
                slot[pos] = make_int2(ei[e], __float_as_int(ew[e]));
            }
        }
        return;
    }

    // ---- gemm path ----
    const int m0 = (blockIdx.x - scatBlocks) * 64;

    auto swz = [](int r, int e) {
        return r * K + ((((e >> 3) ^ (r & 7)) << 3) | (e & 7));
    };

    constexpr int WQ8 = N * K / 8;
    for (int q = tid; q < WQ8; q += 256) {
        int nrow = q / (K / 8);
        int e8   = (q % (K / 8)) * 8;
        uint4 v = *(const uint4*)(Wab + (size_t)nrow * K + e8);
        *(uint4*)&sW[swz(nrow, e8)] = v;
    }
    constexpr int XQ = 64 * (K / 4);
    for (int q = tid; q < XQ; q += 256) {
        int r  = q / (K / 4);
        int k4 = (q % (K / 4)) * 4;
        float4 v = make_float4(0.f, 0.f, 0.f, 0.f);
        int gr = m0 + r;
        if (gr < M) v = *(const float4*)(X + (size_t)gr * K + k4);
        short4 h = make_short4((short)f2bf(v.x), (short)f2bf(v.y),
                               (short)f2bf(v.z), (short)f2bf(v.w));
        *(short4*)&sX[swz(r, k4)] = h;
    }
    __syncthreads();

    const int wv   = tid >> 6;
    const int lane = tid & 63;
    const int mrow = lane & 15;
    const int quad = lane >> 4;

    bf16x8 a[KC];
    #pragma unroll
    for (int kc = 0; kc < KC; ++kc)
        a[kc] = *(const bf16x8*)&sX[swz(wv * 16 + mrow, kc * 32 + quad * 8)];

    #pragma unroll
    for (int nt = 0; nt < NT; ++nt) {
        f32x4 acc = {0.f, 0.f, 0.f, 0.f};
        #pragma unroll
        for (int kc = 0; kc < KC; ++kc) {
            bf16x8 bfr = *(const bf16x8*)&sW[swz(nt * 16 + mrow, kc * 32 + quad * 8)];
            acc = __builtin_amdgcn_mfma_f32_16x16x32_bf16(a[kc], bfr, acc, 0, 0, 0);
        }
        const int col = nt * 16 + mrow;
        ushort_t* dst;
        int cc;
        float bv;
        if (col < N / 2) { dst = OutA; cc = col;         bv = ba[cc]; }
        else             { dst = OutB; cc = col - N / 2; bv = bb[cc]; }
        #pragma unroll
        for (int r = 0; r < 4; ++r) {
            int row = m0 + wv * 16 + quad * 4 + r;
            if (row < M)
                dst[(size_t)row * (N / 2) + cc] = f2bf(acc[r] + bv);
        }
    }
}

// ---------------------------------------------------------------------------
// MFMA fused linear (standalone, used for layer 2) — r13-proven.
// ---------------------------------------------------------------------------
template<int N, int K>
__global__ __launch_bounds__(256, 2)
void gemm_xw_mfma(const float* __restrict__ X, const ushort_t* __restrict__ Wab,
                  const float* __restrict__ ba, const float* __restrict__ bb,
                  ushort_t* __restrict__ OutA, ushort_t* __restrict__ OutB, int M)
{
    constexpr int KC = K / 32;
    constexpr int NT = N / 16;
    __shared__ ushort_t sW[N * K];
    __shared__ ushort_t sX[64 * K];
    const int tid = threadIdx.x;
    const int m0  = blockIdx.x * 64;

    auto swz = [](int r, int e) {
        return r * K + ((((e >> 3) ^ (r & 7)) << 3) | (e & 7));
    };

    constexpr int WQ8 = N * K / 8;
    for (int q = tid; q < WQ8; q += 256) {
        int nrow = q / (K / 8);
        int e8   = (q % (K / 8)) * 8;
        uint4 v = *(const uint4*)(Wab + (size_t)nrow * K + e8);
        *(uint4*)&sW[swz(nrow, e8)] = v;
    }
    constexpr int XQ = 64 * (K / 4);
    for (int q = tid; q < XQ; q += 256) {
        int r  = q / (K / 4);
        int k4 = (q % (K / 4)) * 4;
        float4 v = make_float4(0.f, 0.f, 0.f, 0.f);
        int gr = m0 + r;
        if (gr < M) v = *(const float4*)(X + (size_t)gr * K + k4);
        short4 h = make_short4((short)f2bf(v.x), (short)f2bf(v.y),
                               (short)f2bf(v.z), (short)f2bf(v.w));
        *(short4*)&sX[swz(r, k4)] = h;
    }
    __syncthreads();

    const int wv   = tid >> 6;
    const int lane = tid & 63;
    const int mrow = lane & 15;
    const int quad = lane >> 4;

    bf16x8 a[KC];
    #pragma unroll
    for (int kc = 0; kc < KC; ++kc)
        a[kc] = *(const bf16x8*)&sX[swz(wv * 16 + mrow, kc * 32 + quad * 8)];

    #pragma unroll
    for (int nt = 0; nt < NT; ++nt) {
        f32x4 acc = {0.f, 0.f, 0.f, 0.f};
        #pragma unroll
        for (int kc = 0; kc < KC; ++kc) {
            bf16x8 bfr = *(const bf16x8*)&sW[swz(nt * 16 + mrow, kc * 32 + quad * 8)];
            acc = __builtin_amdgcn_mfma_f32_16x16x32_bf16(a[kc], bfr, acc, 0, 0, 0);
        }
        const int col = nt * 16 + mrow;
        ushort_t* dst;
        int cc;
        float bv;
        if (col < N / 2) { dst = OutA; cc = col;         bv = ba[cc]; }
        else             { dst = OutB; cc = col - N / 2; bv = bb[cc]; }
        #pragma unroll
        for (int r = 0; r < 4; ++r) {
            int row = m0 + wv * 16 + quad * 4 + r;
            if (row < M)
                dst[(size_t)row * (N / 2) + cc] = f2bf(acc[r] + bv);
        }
    }
}

// ---------------------------------------------------------------------------
// Per-node GATv2 attention + aggregation — r13-proven version.
// bf16 xl/xr, LPE=D/4 lanes/edge, 4-deep prefetch, tail + self-loop gathers
// hoisted into the entry prefetch. ACT: 0 = ELU, 1 = softplus + 1e-4.
// ---------------------------------------------------------------------------
template<int D, int ACT>
__global__ __launch_bounds__(256)
void edge_attn(const ushort_t* __restrict__ xl, const ushort_t* __restrict__ xr,
               const float* __restrict__ We, const float* __restrict__ att,
               const float* __restrict__ bias,
               const int* __restrict__ row_off, const int2* __restrict__ slot,
               float* __restrict__ out, int n)
{
    constexpr int LPE = D / 4;                 // lanes per edge
    constexpr int SG  = 64 / LPE;              // edges per round
    const int lane = threadIdx.x & 63;
    const int wid  = threadIdx.x >> 6;
    const int t    = lane % LPE;               // owns dims 4t..4t+3
    const int g    = lane / LPE;               // edge slot within round
    const int node = blockIdx.x * 4 + wid;
    if (node >= n) return;

    auto unpack = [](uint2 d) -> float4 {
        float4 r;
        r.x = __uint_as_float(d.x << 16);
        r.y = __uint_as_float(d.x & 0xffff0000u);
        r.z = __uint_as_float(d.y << 16);
        r.w = __uint_as_float(d.y & 0xffff0000u);
        return r;
    };

    const float4 We4   = *(const float4*)(We   + 4 * t);
    const float4 att4  = *(const float4*)(att  + 4 * t);
    const float4 bias4 = *(const float4*)(bias + 4 * t);
    const float4 xr4   = unpack(*(const uint2*)(xr + (size_t)node * D + 4 * t));

    const int start = row_off[node];
    const int end   = row_off[node + 1];
    const int R  = (end - start) / SG;         // full rounds
    const int jt = start + R * SG;             // tail begin
    const bool has_tail = jt < end;

    // ---- entry prefetch: main pipeline + tail + self-loop all in flight ----
    int2  q[4];
    uint2 xv[4];
    #pragma unroll
    for (int s = 0; s < 4; ++s) {
        if (s < R) {
            q[s]  = slot[start + s * SG + g];
            xv[s] = *(const uint2*)(xl + (size_t)q[s].x * D + 4 * t);
        }
    }
    int2 tq = make_int2(0, 0);
    uint2 tx = make_uint2(0u, 0u);
    if (has_tail) {
        int idx = min(jt + g, end - 1);
        tq = slot[idx];
        tx = *(const uint2*)(xl + (size_t)tq.x * D + 4 * t);
    }
    const uint2 xs = *(const uint2*)(xl + (size_t)node * D + 4 * t); // self

    float denom = 0.f, wsum = 0.f;
    float4 acc = make_float4(0.f, 0.f, 0.f, 0.f);

    auto body = [&](int2 qe, float4 xvv, bool active) {
        float w = __int_as_float(qe.y);
        float4 v;
        v.x = xvv.x + fmaf(w, We4.x, xr4.x);
        v.y = xvv.y + fmaf(w, We4.y, xr4.y);
        v.z = xvv.z + fmaf(w, We4.z, xr4.z);
        v.w = xvv.w + fmaf(w, We4.w, xr4.w);
        float4 m;
        m.x = fmaxf(v.x, 0.2f * v.x);
        m.y = fmaxf(v.y, 0.2f * v.y);
        m.z = fmaxf(v.z, 0.2f * v.z);
        m.w = fmaxf(v.w, 0.2f * v.w);
        float p = att4.x * m.x + att4.y * m.y + att4.z * m.z + att4.w * m.w;
        p = group_reduce<LPE>(p);              // per-edge score, DPP only
        float e = active ? __expf(p) : 0.f;
        wsum  += active ? w : 0.f;
        denom += e;
        acc.x = fmaf(e, xvv.x, acc.x);
        acc.y = fmaf(e, xvv.y, acc.y);
        acc.z = fmaf(e, xvv.z, acc.z);
        acc.w = fmaf(e, xvv.w, acc.w);
    };

    int b = 0;
    for (; b + 4 <= R; b += 4) {               // steady state
        #pragma unroll
        for (int s = 0; s < 4; ++s) {
            int2 cq = q[s]; uint2 cx = xv[s];
            int nr = b + 4 + s;
            if (nr < R) {                      // refill stage s
                q[s]  = slot[start + nr * SG + g];
                xv[s] = *(const uint2*)(xl + (size_t)q[s].x * D + 4 * t);
            }
            body(cq, unpack(cx), true);
        }
    }
    #pragma unroll
    for (int s = 0; s < 4; ++s)                // leftover full rounds
        if (b + s < R) body(q[s], unpack(xv[s]), true);

    if (has_tail)                              // tail round (data prefetched)
        body(tq, unpack(tx), (jt + g) < end);

    // combine partials across the SG subgroups (once per node)
    #pragma unroll
    for (int mask = LPE; mask < 64; mask <<= 1) {
        denom += __shfl_xor(denom, mask);
        wsum  += __shfl_xor(wsum,  mask);
        acc.x += __shfl_xor(acc.x, mask);
        acc.y += __shfl_xor(acc.y, mask);
        acc.z += __shfl_xor(acc.z, mask);
        acc.w += __shfl_xor(acc.w, mask);
    }

    {   // self-loop: w = mean of incoming edge weights (xs prefetched)
        float w = wsum / (float)max(end - start, 1);
        float4 xvs = unpack(xs);
        float4 v;
        v.x = xvs.x + fmaf(w, We4.x, xr4.x);
        v.y = xvs.y + fmaf(w, We4.y, xr4.y);
        v.z = xvs.z + fmaf(w, We4.z, xr4.z);
        v.w = xvs.w + fmaf(w, We4.w, xr4.w);
        float4 m;
        m.x = fmaxf(v.x, 0.2f * v.x);
        m.y = fmaxf(v.y, 0.2f * v.y);
        m.z = fmaxf(v.z, 0.2f * v.z);
        m.w = fmaxf(v.w, 0.2f * v.w);
        float p = att4.x * m.x + att4.y * m.y + att4.z * m.z + att4.w * m.w;
        p = group_reduce<LPE>(p);
        float e = __expf(p);
        denom += e;
        acc.x = fmaf(e, xvs.x, acc.x);
        acc.y = fmaf(e, xvs.y, acc.y);
        acc.z = fmaf(e, xvs.z, acc.z);
        acc.w = fmaf(e, xvs.w, acc.w);
    }

    float4 res;
    res.x = acc.x / denom + bias4.x;
    res.y = acc.y / denom + bias4.y;
    res.z = acc.z / denom + bias4.z;
    res.w = acc.w / denom + bias4.w;
    if (ACT == 0) {
        // ELU via hw exp: max(r,0) + exp(min(r,0)) - 1   (exact for r>=0)
        res.x = fmaxf(res.x, 0.f) + __expf(fminf(res.x, 0.f)) - 1.f;
        res.y = fmaxf(res.y, 0.f) + __expf(fminf(res.y, 0.f)) - 1.f;
        res.z = fmaxf(res.z, 0.f) + __expf(fminf(res.z, 0.f)) - 1.f;
        res.w = fmaxf(res.w, 0.f) + __expf(fminf(res.w, 0.f)) - 1.f;
    } else {
        // softplus via hw exp/log + 1e-4
        res.x = fmaxf(res.x, 0.f) + __logf(1.f + __expf(-fabsf(res.x))) + 1e-4f;
        res.y = fmaxf(res.y, 0.f) + __logf(1.f + __expf(-fabsf(res.y))) + 1e-4f;
        res.z = fmaxf(res.z, 0.f) + __logf(1.f + __expf(-fabsf(res.z))) + 1e-4f;
        res.w = fmaxf(res.w, 0.f) + __logf(1.f + __expf(-fabsf(res.w))) + 1e-4f;
    }
    if (g == 0)
        *(float4*)(out + (size_t)node * D + 4 * t) = res;
}

// ---------------------------------------------------------------------------
extern "C" void kernel_launch(void* const* d_in, const int* in_sizes, int n_in,
                              void* d_out, int out_size, void* d_ws, size_t ws_size,
                              hipStream_t stream)
{
    const float* x     = (const float*)d_in[0];
    const int*   ei    = (const int*)d_in[1];     // (2, E) int32
    const float* ew    = (const float*)d_in[2];
    const float* Wl1   = (const float*)d_in[3];
    const float* bl1   = (const float*)d_in[4];
    const float* Wr1   = (const float*)d_in[5];
    const float* br1   = (const float*)d_in[6];
    const float* We1   = (const float*)d_in[7];
    const float* att1  = (const float*)d_in[8];
    const float* bias1 = (const float*)d_in[9];
    const float* Wl2   = (const float*)d_in[10];
    const float* bl2   = (const float*)d_in[11];
    const float* Wr2   = (const float*)d_in[12];
    const float* br2   = (const float*)d_in[13];
    const float* We2   = (const float*)d_in[14];
    const float* att2  = (const float*)d_in[15];
    const float* bias2 = (const float*)d_in[16];
    float* out = (float*)d_out;

    const int n = in_sizes[0] / 128;
    const int E = in_sizes[2];
    const int NB = (n + 255) / 256;               // 196 (<= 256 required)
    const int EPB = (E + NBLK - 1) / NBLK;        // edges per histogram block
    const int scatBlocks = (E + 2047) / 2048;     // 8 edges/thread
    const int gemmBlocks = (n + 63) / 64;

    char* wp = (char*)d_ws;
    auto carve = [&](size_t bytes) -> void* {
        void* p = (void*)wp;
        wp += (bytes + 255) & ~(size_t)255;
        return p;
    };
    int*      cnt     = (int*)     carve((size_t)n * 4);
    int*      row_off = (int*)     carve((size_t)(n + 1) * 4);
    ushort_t* lrank   = (ushort_t*)carve((size_t)E * 2);
    ushort_t* histG   = (ushort_t*)carve((size_t)NBLK * n * 2);   // -> boff
    int*      bsums   = (int*)     carve((size_t)256 * 4);
    int2*     slot    = (int2*)    carve((size_t)E * 8);
    ushort_t* wab1    = (ushort_t*)carve((size_t)2 * 64 * 128 * 2);
    ushort_t* wab2    = (ushort_t*)carve((size_t)2 * 32 * 64 * 2);
    ushort_t* xl1     = (ushort_t*)carve((size_t)n * 64 * 2);
    ushort_t* xr1     = (ushort_t*)carve((size_t)n * 64 * 2);
    float*    hbuf    = (float*)   carve((size_t)n * 64 * 4);
    ushort_t* xl2     = (ushort_t*)carve((size_t)n * 32 * 2);
    ushort_t* xr2     = (ushort_t*)carve((size_t)n * 32 * 2);

    setup_kernel<<<256, 256, 0, stream>>>(Wl1, Wr1, Wl2, Wr2, wab1, wab2);

    // CSR build, zero global atomics
    count_hist<<<NBLK, 256, 0, stream>>>(ei, lrank, histG, E, n, EPB);
    col_scan  <<<NB, 256, 0, stream>>>(histG, cnt, n);
    scan_p1   <<<NB, 256, 0, stream>>>(cnt, bsums, n);
    scan_p3   <<<NB, 256, 0, stream>>>(cnt, bsums, row_off, n, NB);

    // fused: scatter (no atomics) || layer-1 GEMM
    scat_plus_gemm<128, 128><<<scatBlocks + gemmBlocks, 256, 0, stream>>>(
        ei, ew, row_off, lrank, histG, slot, E, n, EPB, scatBlocks,
        x, wab1, bl1, br1, xl1, xr1, n);

    edge_attn<64, 0><<<(n + 3) / 4, 256, 0, stream>>>(xl1, xr1, We1, att1, bias1,
                                                      row_off, slot, hbuf, n);
    gemm_xw_mfma<64, 64><<<(n + 63) / 64, 256, 0, stream>>>(hbuf, wab2, bl2, br2,
                                                            xl2, xr2, n);
    edge_attn<32, 1><<<(n + 3) / 4, 256, 0, stream>>>(xl2, xr2, We2, att2, bias2,
                                                      row_off, slot, out, n);
}

// Round 5
// 241.906 us; speedup vs baseline: 1.0085x; 1.0085x over previous
//
#include <hip/hip_runtime.h>
#include <math.h>

typedef unsigned short ushort_t;
typedef __attribute__((ext_vector_type(8))) short bf16x8;   // MFMA A/B frag (4 VGPR)
typedef __attribute__((ext_vector_type(4))) float f32x4;    // MFMA C/D frag

// r4 post-mortem: scat's random boff gather into the 12.8MB histG table blew
// FETCH 14->53MB (64B line per 2B read, beyond L2) and kept the dispatch at
// ~50us. r5: scatter block b stages ONLY row b of boff (100KB, contiguous)
// into LDS; row_off gathers hit the L2-resident 200KB table. Also 9->7
// dispatches (setup folded into count_hist; col_scan+scan_p1 fused, gemm1
// rides on the colscan dispatch instead of the 100KB-LDS scatter).
#define NBLK  128         // histogram blocks (each owns E/NBLK edges)
#define MAXNH 25024       // LDS uints for packed 2x16b counters (n <= 50048)

// ---------------------------------------------------------------------------
// DPP-based add: x += x[lane ^ pattern], pure VALU.
// ---------------------------------------------------------------------------
template<int CTRL>
__device__ __forceinline__ float dpp_addf(float x)
{
    int y = __builtin_amdgcn_update_dpp(0, __float_as_int(x), CTRL, 0xf, 0xf, true);
    return x + __int_as_float(y);
}

template<int LPE>
__device__ __forceinline__ float group_reduce(float p)
{
    p = dpp_addf<0xB1>(p);                           // xor 1
    p = dpp_addf<0x4E>(p);                           // xor 2
    if constexpr (LPE >= 8)  p = dpp_addf<0x141>(p); // xor 7
    if constexpr (LPE >= 16) p = dpp_addf<0x140>(p); // xor 15
    return p;
}

__device__ __forceinline__ ushort_t f2bf(float f)
{
    unsigned u = __float_as_uint(f);
    return (ushort_t)((u + 0x7fffu + ((u >> 16) & 1u)) >> 16);   // RNE
}

// ---------------------------------------------------------------------------
// Kernel A: per-block LDS histogram (packed 2x16b counters, CU-local atomics)
// + edge local ranks. Last block instead converts the weight matrices to bf16
// (the old setup kernel — folded here to save a dispatch).
// ---------------------------------------------------------------------------
__global__ __launch_bounds__(256, 1)
void count_hist(const int* __restrict__ ei, ushort_t* __restrict__ lrank,
                ushort_t* __restrict__ histG,
                const float* __restrict__ Wl1, const float* __restrict__ Wr1,
                const float* __restrict__ Wl2, const float* __restrict__ Wr2,
                ushort_t* __restrict__ wab1, ushort_t* __restrict__ wab2,
                int E, int n, int EPB)
{
    const int tid = threadIdx.x;
    const int b   = blockIdx.x;

    if (b == NBLK) {                               // ---- setup tail block ----
        for (int k = tid; k < 2 * 64 * 128; k += 256)
            wab1[k] = f2bf(k < 64 * 128 ? Wl1[k] : Wr1[k - 64 * 128]);
        for (int k = tid; k < 2 * 32 * 64; k += 256)
            wab2[k] = f2bf(k < 32 * 64 ? Wl2[k] : Wr2[k - 32 * 64]);
        return;
    }

    __shared__ unsigned h[MAXNH];                  // 100 KB
    const int nh = (n + 1) >> 1;
    for (int i = tid; i < nh; i += 256) h[i] = 0u;
    __syncthreads();

    const int e0 = b * EPB;
    const int e1 = min(e0 + EPB, E);
    for (int e = e0 + tid; e < e1; e += 256) {
        int d = ei[E + e];
        unsigned sh  = (unsigned)(d & 1) * 16u;
        unsigned old = atomicAdd(&h[d >> 1], 1u << sh);     // LDS atomic
        lrank[e] = (ushort_t)((old >> sh) & 0xffffu);
    }
    __syncthreads();

    ushort_t* row = histG + (size_t)b * n;         // coalesced row dump
    for (int i = tid; i < n; i += 256) {
        unsigned v = h[i >> 1];
        row[i] = (ushort_t)((v >> ((i & 1) * 16)) & 0xffffu);
    }
}

// ---------------------------------------------------------------------------
// Kernel B: fused [col_scan + scan_p1 | gemm1].
// colscan blocks: per-node exclusive prefix across NBLK rows (histG -> boff,
// in place), dense cnt, AND the per-tile reduce that used to be scan_p1
// (same 256-node tiling -> free). gemm blocks: layer-1 MFMA GEMM (needs only
// x + wab1, independent of the CSR chain -> overlaps it).
// GEMM layouts HW-verified (m89/m91); XOR-granule swizzle kills conflicts.
// ---------------------------------------------------------------------------
template<int N, int K>
__global__ __launch_bounds__(256, 2)
void colscan_plus_gemm(ushort_t* __restrict__ histG, int* __restrict__ cnt,
                       int* __restrict__ bsums, int n, int csBlocks,
                       const float* __restrict__ X, const ushort_t* __restrict__ Wab,
                       const float* __restrict__ ba, const float* __restrict__ bb,
                       ushort_t* __restrict__ OutA, ushort_t* __restrict__ OutB,
                       int M)
{
    constexpr int KC = K / 32;
    constexpr int NT = N / 16;
    __shared__ ushort_t sW[N * K];
    __shared__ ushort_t sX[64 * K];
    __shared__ int s[256];
    const int tid = threadIdx.x;

    if (blockIdx.x < csBlocks) {                // ---- colscan + p1 path ----
        int idx = blockIdx.x * 256 + tid;
        unsigned acc = 0;
        if (idx < n) {
            #pragma unroll 1
            for (int b0 = 0; b0 < NBLK; b0 += 16) {
                ushort_t c[16];
                #pragma unroll
                for (int j = 0; j < 16; ++j)
                    c[j] = histG[(size_t)(b0 + j) * n + idx];
                #pragma unroll
                for (int j = 0; j < 16; ++j) {
                    unsigned cc = c[j];
                    histG[(size_t)(b0 + j) * n + idx] = (ushort_t)acc;
                    acc += cc;
                }
            }
            cnt[idx] = (int)acc;
        }
        s[tid] = (idx < n) ? (int)acc : 0;      // fused scan_p1 tile reduce
        __syncthreads();
        #pragma unroll
        for (int off = 128; off >= 1; off >>= 1) {
            if (tid < off) s[tid] += s[tid + off];
            __syncthreads();
        }
        if (tid == 0) bsums[blockIdx.x] = s[0];
        return;
    }

    // ---- gemm path ----
    const int m0 = (blockIdx.x - csBlocks) * 64;

    auto swz = [](int r, int e) {
        return r * K + ((((e >> 3) ^ (r & 7)) << 3) | (e & 7));
    };

    constexpr int WQ8 = N * K / 8;
    for (int q = tid; q < WQ8; q += 256) {
        int nrow = q / (K / 8);
        int e8   = (q % (K / 8)) * 8;
        uint4 v = *(const uint4*)(Wab + (size_t)nrow * K + e8);
        *(uint4*)&sW[swz(nrow, e8)] = v;
    }
    constexpr int XQ = 64 * (K / 4);
    for (int q = tid; q < XQ; q += 256) {
        int r  = q / (K / 4);
        int k4 = (q % (K / 4)) * 4;
        float4 v = make_float4(0.f, 0.f, 0.f, 0.f);
        int gr = m0 + r;
        if (gr < M) v = *(const float4*)(X + (size_t)gr * K + k4);
        short4 h = make_short4((short)f2bf(v.x), (short)f2bf(v.y),
                               (short)f2bf(v.z), (short)f2bf(v.w));
        *(short4*)&sX[swz(r, k4)] = h;
    }
    __syncthreads();

    const int wv   = tid >> 6;
    const int lane = tid & 63;
    const int mrow = lane & 15;
    const int quad = lane >> 4;

    bf16x8 a[KC];
    #pragma unroll
    for (int kc = 0; kc < KC; ++kc)
        a[kc] = *(const bf16x8*)&sX[swz(wv * 16 + mrow, kc * 32 + quad * 8)];

    #pragma unroll
    for (int nt = 0; nt < NT; ++nt) {
        f32x4 acc = {0.f, 0.f, 0.f, 0.f};
        #pragma unroll
        for (int kc = 0; kc < KC; ++kc) {
            bf16x8 bfr = *(const bf16x8*)&sW[swz(nt * 16 + mrow, kc * 32 + quad * 8)];
            acc = __builtin_amdgcn_mfma_f32_16x16x32_bf16(a[kc], bfr, acc, 0, 0, 0);
        }
        const int col = nt * 16 + mrow;
        ushort_t* dst;
        int cc;
        float bv;
        if (col < N / 2) { dst = OutA; cc = col;         bv = ba[cc]; }
        else             { dst = OutB; cc = col - N / 2; bv = bb[cc]; }
        #pragma unroll
        for (int r = 0; r < 4; ++r) {
            int row = m0 + wv * 16 + quad * 4 + r;
            if (row < M)
                dst[(size_t)row * (N / 2) + cc] = f2bf(acc[r] + bv);
        }
    }
}

// ---------------------------------------------------------------------------
// Kernel C: scan_p3 (unchanged, r13-proven) — row_off from cnt + bsums.
// ---------------------------------------------------------------------------
__global__ __launch_bounds__(256)
void scan_p3(const int* __restrict__ cnt, const int* __restrict__ bsums,
             int* __restrict__ row_off, int n, int nb)
{
    __shared__ int sb[256];
    __shared__ int s[256];
    const int tid = threadIdx.x;

    int bv = (tid < nb) ? bsums[tid] : 0;
    sb[tid] = bv;
    __syncthreads();
    #pragma unroll
    for (int off = 1; off < 256; off <<= 1) {       // inclusive scan of bsums
        int t = (tid >= off) ? sb[tid - off] : 0;
        __syncthreads();
        sb[tid] += t;
        __syncthreads();
    }
    int excl_t = sb[tid] - bv;                      // exclusive
    __syncthreads();
    sb[tid] = excl_t;
    __syncthreads();
    const int base = sb[blockIdx.x];

    int gi = blockIdx.x * 256 + tid;
    int c = (gi < n) ? cnt[gi] : 0;
    s[tid] = c;
    __syncthreads();
    #pragma unroll
    for (int off = 1; off < 256; off <<= 1) {       // inclusive scan of tile
        int t = (tid >= off) ? s[tid - off] : 0;
        __syncthreads();
        s[tid] += t;
        __syncthreads();
    }
    if (gi < n) {
        int excl = base + s[tid] - c;
        row_off[gi] = excl;
        if (gi == n - 1) row_off[n] = excl + c;     // == E
    }
}

// ---------------------------------------------------------------------------
// Kernel D: scatter, LDS-staged base offsets. Block b loads boff row b
// (contiguous 100KB) into LDS, then streams its OWN edge slice (same slice
// as count_hist block b, so hb == b exactly): pos = row_off[d] (L2) +
// sb[d] (LDS) + lrank[e] (coalesced). No atomics, no random beyond-L2 reads.
// ---------------------------------------------------------------------------
__global__ __launch_bounds__(256, 1)
void scat_lds(const int* __restrict__ ei, const float* __restrict__ ew,
              const int* __restrict__ row_off, const ushort_t* __restrict__ lrank,
              const ushort_t* __restrict__ boff, int2* __restrict__ slot,
              int E, int n, int EPB)
{
    __shared__ ushort_t sb[2 * MAXNH];             // 100 KB (n <= 50048)
    const int tid = threadIdx.x;
    const int b   = blockIdx.x;

    const ushort_t* row = boff + (size_t)b * n;
    {   // coalesced stage (dword granularity; row byte-offset is 4B-aligned
        // when n is even; fall back to ushort loop otherwise)
        if ((n & 1) == 0 && (((size_t)b * n) & 1) == 0) {
            const unsigned* r32 = (const unsigned*)row;
            unsigned* s32 = (unsigned*)sb;
            for (int i = tid; i < (n >> 1); i += 256) s32[i] = r32[i];
        } else {
            for (int i = tid; i < n; i += 256) sb[i] = row[i];
        }
    }
    __syncthreads();

    const int e0 = b * EPB;
    const int e1 = min(e0 + EPB, E);
    for (int base = e0 + tid; base < e1; base += 256 * 4) {
        int dd[4], ss[4];
        ushort_t rr[4];
        float ww[4];
        #pragma unroll
        for (int j = 0; j < 4; ++j) {              // batch loads 4 deep
            int e = base + j * 256;
            if (e < e1) {
                dd[j] = ei[E + e];
                rr[j] = lrank[e];
                ss[j] = ei[e];
                ww[j] = ew[e];
            }
        }
        #pragma unroll
        for (int j = 0; j < 4; ++j) {
            int e = base + j * 256;
            if (e < e1) {
                int pos = row_off[dd[j]] + (int)sb[dd[j]] + (int)rr[j];
                slot[pos] = make_int2(ss[j], __float_as_int(ww[j]));
            }
        }
    }
}

// ---------------------------------------------------------------------------
// MFMA fused linear (standalone, used for layer 2) — r13-proven.
// ---------------------------------------------------------------------------
template<int N, int K>
__global__ __launch_bounds__(256, 2)
void gemm_xw_mfma(const float* __restrict__ X, const ushort_t* __restrict__ Wab,
                  const float* __restrict__ ba, const float* __restrict__ bb,
                  ushort_t* __restrict__ OutA, ushort_t* __restrict__ OutB, int M)
{
    constexpr int KC = K / 32;
    constexpr int NT = N / 16;
    __shared__ ushort_t sW[N * K];
    __shared__ ushort_t sX[64 * K];
    const int tid = threadIdx.x;
    const int m0  = blockIdx.x * 64;

    auto swz = [](int r, int e) {
        return r * K + ((((e >> 3) ^ (r & 7)) << 3) | (e & 7));
    };

    constexpr int WQ8 = N * K / 8;
    for (int q = tid; q < WQ8; q += 256) {
        int nrow = q / (K / 8);
        int e8   = (q % (K / 8)) * 8;
        uint4 v = *(const uint4*)(Wab + (size_t)nrow * K + e8);
        *(uint4*)&sW[swz(nrow, e8)] = v;
    }
    constexpr int XQ = 64 * (K / 4);
    for (int q = tid; q < XQ; q += 256) {
        int r  = q / (K / 4);
        int k4 = (q % (K / 4)) * 4;
        float4 v = make_float4(0.f, 0.f, 0.f, 0.f);
        int gr = m0 + r;
        if (gr < M) v = *(const float4*)(X + (size_t)gr * K + k4);
        short4 h = make_short4((short)f2bf(v.x), (short)f2bf(v.y),
                               (short)f2bf(v.z), (short)f2bf(v.w));
        *(short4*)&sX[swz(r, k4)] = h;
    }
    __syncthreads();

    const int wv   = tid >> 6;
    const int lane = tid & 63;
    const int mrow = lane & 15;
    const int quad = lane >> 4;

    bf16x8 a[KC];
    #pragma unroll
    for (int kc = 0; kc < KC; ++kc)
        a[kc] = *(const bf16x8*)&sX[swz(wv * 16 + mrow, kc * 32 + quad * 8)];

    #pragma unroll
    for (int nt = 0; nt < NT; ++nt) {
        f32x4 acc = {0.f, 0.f, 0.f, 0.f};
        #pragma unroll
        for (int kc = 0; kc < KC; ++kc) {
            bf16x8 bfr = *(const bf16x8*)&sW[swz(nt * 16 + mrow, kc * 32 + quad * 8)];
            acc = __builtin_amdgcn_mfma_f32_16x16x32_bf16(a[kc], bfr, acc, 0, 0, 0);
        }
        const int col = nt * 16 + mrow;
        ushort_t* dst;
        int cc;
        float bv;
        if (col < N / 2) { dst = OutA; cc = col;         bv = ba[cc]; }
        else             { dst = OutB; cc = col - N / 2; bv = bb[cc]; }
        #pragma unroll
        for (int r = 0; r < 4; ++r) {
            int row = m0 + wv * 16 + quad * 4 + r;
            if (row < M)
                dst[(size_t)row * (N / 2) + cc] = f2bf(acc[r] + bv);
        }
    }
}

// ---------------------------------------------------------------------------
// Per-node GATv2 attention + aggregation — r13-proven version.
// bf16 xl/xr, LPE=D/4 lanes/edge, 4-deep prefetch, tail + self-loop gathers
// hoisted into the entry prefetch. ACT: 0 = ELU, 1 = softplus + 1e-4.
// ---------------------------------------------------------------------------
template<int D, int ACT>
__global__ __launch_bounds__(256)
void edge_attn(const ushort_t* __restrict__ xl, const ushort_t* __restrict__ xr,
               const float* __restrict__ We, const float* __restrict__ att,
               const float* __restrict__ bias,
               const int* __restrict__ row_off, const int2* __restrict__ slot,
               float* __restrict__ out, int n)
{
    constexpr int LPE = D / 4;                 // lanes per edge
    constexpr int SG  = 64 / LPE;              // edges per round
    const int lane = threadIdx.x & 63;
    const int wid  = threadIdx.x >> 6;
    const int t    = lane % LPE;               // owns dims 4t..4t+3
    const int g    = lane / LPE;               // edge slot within round
    const int node = blockIdx.x * 4 + wid;
    if (node >= n) return;

    auto unpack = [](uint2 d) -> float4 {
        float4 r;
        r.x = __uint_as_float(d.x << 16);
        r.y = __uint_as_float(d.x & 0xffff0000u);
        r.z = __uint_as_float(d.y << 16);
        r.w = __uint_as_float(d.y & 0xffff0000u);
        return r;
    };

    const float4 We4   = *(const float4*)(We   + 4 * t);
    const float4 att4  = *(const float4*)(att  + 4 * t);
    const float4 bias4 = *(const float4*)(bias + 4 * t);
    const float4 xr4   = unpack(*(const uint2*)(xr + (size_t)node * D + 4 * t));

    const int start = row_off[node];
    const int end   = row_off[node + 1];
    const int R  = (end - start) / SG;         // full rounds
    const int jt = start + R * SG;             // tail begin
    const bool has_tail = jt < end;

    // ---- entry prefetch: main pipeline + tail + self-loop all in flight ----
    int2  q[4];
    uint2 xv[4];
    #pragma unroll
    for (int s = 0; s < 4; ++s) {
        if (s < R) {
            q[s]  = slot[start + s * SG + g];
            xv[s] = *(const uint2*)(xl + (size_t)q[s].x * D + 4 * t);
        }
    }
    int2 tq = make_int2(0, 0);
    uint2 tx = make_uint2(0u, 0u);
    if (has_tail) {
        int idx = min(jt + g, end - 1);
        tq = slot[idx];
        tx = *(const uint2*)(xl + (size_t)tq.x * D + 4 * t);
    }
    const uint2 xs = *(const uint2*)(xl + (size_t)node * D + 4 * t); // self

    float denom = 0.f, wsum = 0.f;
    float4 acc = make_float4(0.f, 0.f, 0.f, 0.f);

    auto body = [&](int2 qe, float4 xvv, bool active) {
        float w = __int_as_float(qe.y);
        float4 v;
        v.x = xvv.x + fmaf(w, We4.x, xr4.x);
        v.y = xvv.y + fmaf(w, We4.y, xr4.y);
        v.z = xvv.z + fmaf(w, We4.z, xr4.z);
        v.w = xvv.w + fmaf(w, We4.w, xr4.w);
        float4 m;
        m.x = fmaxf(v.x, 0.2f * v.x);
        m.y = fmaxf(v.y, 0.2f * v.y);
        m.z = fmaxf(v.z, 0.2f * v.z);
        m.w = fmaxf(v.w, 0.2f * v.w);
        float p = att4.x * m.x + att4.y * m.y + att4.z * m.z + att4.w * m.w;
        p = group_reduce<LPE>(p);              // per-edge score, DPP only
        float e = active ? __expf(p) : 0.f;
        wsum  += active ? w : 0.f;
        denom += e;
        acc.x = fmaf(e, xvv.x, acc.x);
        acc.y = fmaf(e, xvv.y, acc.y);
        acc.z = fmaf(e, xvv.z, acc.z);
        acc.w = fmaf(e, xvv.w, acc.w);
    };

    int b = 0;
    for (; b + 4 <= R; b += 4) {               // steady state
        #pragma unroll
        for (int s = 0; s < 4; ++s) {
            int2 cq = q[s]; uint2 cx = xv[s];
            int nr = b + 4 + s;
            if (nr < R) {                      // refill stage s
                q[s]  = slot[start + nr * SG + g];
                xv[s] = *(const uint2*)(xl + (size_t)q[s].x * D + 4 * t);
            }
            body(cq, unpack(cx), true);
        }
    }
    #pragma unroll
    for (int s = 0; s < 4; ++s)                // leftover full rounds
        if (b + s < R) body(q[s], unpack(xv[s]), true);

    if (has_tail)                              // tail round (data prefetched)
        body(tq, unpack(tx), (jt + g) < end);

    // combine partials across the SG subgroups (once per node)
    #pragma unroll
    for (int mask = LPE; mask < 64; mask <<= 1) {
        denom += __shfl_xor(denom, mask);
        wsum  += __shfl_xor(wsum,  mask);
        acc.x += __shfl_xor(acc.x, mask);
        acc.y += __shfl_xor(acc.y, mask);
        acc.z += __shfl_xor(acc.z, mask);
        acc.w += __shfl_xor(acc.w, mask);
    }

    {   // self-loop: w = mean of incoming edge weights (xs prefetched)
        float w = wsum / (float)max(end - start, 1);
        float4 xvs = unpack(xs);
        float4 v;
        v.x = xvs.x + fmaf(w, We4.x, xr4.x);
        v.y = xvs.y + fmaf(w, We4.y, xr4.y);
        v.z = xvs.z + fmaf(w, We4.z, xr4.z);
        v.w = xvs.w + fmaf(w, We4.w, xr4.w);
        float4 m;
        m.x = fmaxf(v.x, 0.2f * v.x);
        m.y = fmaxf(v.y, 0.2f * v.y);
        m.z = fmaxf(v.z, 0.2f * v.z);
        m.w = fmaxf(v.w, 0.2f * v.w);
        float p = att4.x * m.x + att4.y * m.y + att4.z * m.z + att4.w * m.w;
        p = group_reduce<LPE>(p);
        float e = __expf(p);
        denom += e;
        acc.x = fmaf(e, xvs.x, acc.x);
        acc.y = fmaf(e, xvs.y, acc.y);
        acc.z = fmaf(e, xvs.z, acc.z);
        acc.w = fmaf(e, xvs.w, acc.w);
    }

    float4 res;
    res.x = acc.x / denom + bias4.x;
    res.y = acc.y / denom + bias4.y;
    res.z = acc.z / denom + bias4.z;
    res.w = acc.w / denom + bias4.w;
    if (ACT == 0) {
        // ELU via hw exp: max(r,0) + exp(min(r,0)) - 1   (exact for r>=0)
        res.x = fmaxf(res.x, 0.f) + __expf(fminf(res.x, 0.f)) - 1.f;
        res.y = fmaxf(res.y, 0.f) + __expf(fminf(res.y, 0.f)) - 1.f;
        res.z = fmaxf(res.z, 0.f) + __expf(fminf(res.z, 0.f)) - 1.f;
        res.w = fmaxf(res.w, 0.f) + __expf(fminf(res.w, 0.f)) - 1.f;
    } else {
        // softplus via hw exp/log + 1e-4
        res.x = fmaxf(res.x, 0.f) + __logf(1.f + __expf(-fabsf(res.x))) + 1e-4f;
        res.y = fmaxf(res.y, 0.f) + __logf(1.f + __expf(-fabsf(res.y))) + 1e-4f;
        res.z = fmaxf(res.z, 0.f) + __logf(1.f + __expf(-fabsf(res.z))) + 1e-4f;
        res.w = fmaxf(res.w, 0.f) + __logf(1.f + __expf(-fabsf(res.w))) + 1e-4f;
    }
    if (g == 0)
        *(float4*)(out + (size_t)node * D + 4 * t) = res;
}

// ---------------------------------------------------------------------------
extern "C" void kernel_launch(void* const* d_in, const int* in_sizes, int n_in,
                              void* d_out, int out_size, void* d_ws, size_t ws_size,
                              hipStream_t stream)
{
    const float* x     = (const float*)d_in[0];
    const int*   ei    = (const int*)d_in[1];     // (2, E) int32
    const float* ew    = (const float*)d_in[2];
    const float* Wl1   = (const float*)d_in[3];
    const float* bl1   = (const float*)d_in[4];
    const float* Wr1   = (const float*)d_in[5];
    const float* br1   = (const float*)d_in[6];
    const float* We1   = (const float*)d_in[7];
    const float* att1  = (const float*)d_in[8];
    const float* bias1 = (const float*)d_in[9];
    const float* Wl2   = (const float*)d_in[10];
    const float* bl2   = (const float*)d_in[11];
    const float* Wr2   = (const float*)d_in[12];
    const float* br2   = (const float*)d_in[13];
    const float* We2   = (const float*)d_in[14];
    const float* att2  = (const float*)d_in[15];
    const float* bias2 = (const float*)d_in[16];
    float* out = (float*)d_out;

    const int n = in_sizes[0] / 128;
    const int E = in_sizes[2];
    const int NB = (n + 255) / 256;               // 196 (<= 256 required)
    const int EPB = (E + NBLK - 1) / NBLK;        // edges per histogram block
    const int gemmBlocks = (n + 63) / 64;

    char* wp = (char*)d_ws;
    auto carve = [&](size_t bytes) -> void* {
        void* p = (void*)wp;
        wp += (bytes + 255) & ~(size_t)255;
        return p;
    };
    int*      cnt     = (int*)     carve((size_t)n * 4);
    int*      row_off = (int*)     carve((size_t)(n + 1) * 4);
    ushort_t* lrank   = (ushort_t*)carve((size_t)E * 2);
    ushort_t* histG   = (ushort_t*)carve((size_t)NBLK * n * 2);   // -> boff
    int*      bsums   = (int*)     carve((size_t)256 * 4);
    int2*     slot    = (int2*)    carve((size_t)E * 8);
    ushort_t* wab1    = (ushort_t*)carve((size_t)2 * 64 * 128 * 2);
    ushort_t* wab2    = (ushort_t*)carve((size_t)2 * 32 * 64 * 2);
    ushort_t* xl1     = (ushort_t*)carve((size_t)n * 64 * 2);
    ushort_t* xr1     = (ushort_t*)carve((size_t)n * 64 * 2);
    float*    hbuf    = (float*)   carve((size_t)n * 64 * 4);
    ushort_t* xl2     = (ushort_t*)carve((size_t)n * 32 * 2);
    ushort_t* xr2     = (ushort_t*)carve((size_t)n * 32 * 2);

    // A: histograms + local ranks (+ weight conversion in tail block)
    count_hist<<<NBLK + 1, 256, 0, stream>>>(ei, lrank, histG,
                                             Wl1, Wr1, Wl2, Wr2, wab1, wab2,
                                             E, n, EPB);
    // B: [col_scan + scan_p1] || layer-1 GEMM
    colscan_plus_gemm<128, 128><<<NB + gemmBlocks, 256, 0, stream>>>(
        histG, cnt, bsums, n, NB, x, wab1, bl1, br1, xl1, xr1, n);
    // C: row_off
    scan_p3<<<NB, 256, 0, stream>>>(cnt, bsums, row_off, n, NB);
    // D: scatter with LDS-staged per-row base offsets
    scat_lds<<<NBLK, 256, 0, stream>>>(ei, ew, row_off, lrank, histG, slot,
                                       E, n, EPB);

    edge_attn<64, 0><<<(n + 3) / 4, 256, 0, stream>>>(xl1, xr1, We1, att1, bias1,
                                                      row_off, slot, hbuf, n);
    gemm_xw_mfma<64, 64><<<(n + 63) / 64, 256, 0, stream>>>(hbuf, wab2, bl2, br2,
                                                            xl2, xr2, n);
    edge_attn<32, 1><<<(n + 3) / 4, 256, 0, stream>>>(xl2, xr2, We2, att2, bias2,
                                                      row_off, slot, out, n);
}